// Round 1
// baseline (170.098 us; speedup 1.0000x reference)
//
#include <hip/hip_runtime.h>

// LengthRegulator: out[b,pos,:] = x[b, src(b,pos), :] masked by pos < total[b]
// B=16, T=1024, D=512, MAXLEN=4096 (fixed by setup_inputs()).

#define BB 16
#define TT 1024
#define DD 512
#define MAXLEN 4096

typedef float f32x4 __attribute__((ext_vector_type(4)));

// ---------------------------------------------------------------------------
// Kernel 1: per-batch cumsum + inverse src table.
// One block per batch, 1024 threads (1 per t). Wave-level shfl scan, one LDS
// round over the 16 wave sums, then each thread scatters its run (d <= 7 ints)
// and strided tail-fill of -1.
// ---------------------------------------------------------------------------
__global__ __launch_bounds__(1024) void build_src_kernel(
    const int* __restrict__ dur, int* __restrict__ srcTab) {
  const int b = blockIdx.x;
  const int t = threadIdx.x;     // 0..1023 == source index
  const int lane = t & 63;
  const int wid = t >> 6;        // 0..15

  __shared__ int wsum[16];

  int d = dur[b * TT + t];
  d = d > 0 ? d : 0;

  // inclusive scan within the wave
  int v = d;
#pragma unroll
  for (int off = 1; off < 64; off <<= 1) {
    int o = __shfl_up(v, off, 64);
    if (lane >= off) v += o;
  }
  if (lane == 63) wsum[wid] = v;
  __syncthreads();

  // exclusive base across waves + grand total (16 LDS broadcast reads)
  int base = 0, total = 0;
#pragma unroll
  for (int w = 0; w < 16; ++w) {
    const int s = wsum[w];
    total += s;
    if (w < wid) base += s;
  }
  const int incl = base + v;   // csum through t inclusive

  int* st = srcTab + b * MAXLEN;
  for (int p = incl - d; p < incl; ++p) st[p] = t;       // run of length d
  for (int p = total + t; p < MAXLEN; p += 1024) st[p] = -1;  // masked tail
}

// ---------------------------------------------------------------------------
// Kernel 2: one wave (64 lanes) per output row of 512 floats (128 float4).
// 4 waves / 256-thread block. XCD-aware swizzle: 16384 blocks, blockIdx%8 is
// the XCD -> give each XCD a contiguous 2048-block (= 2 batches = 4 MiB of x,
// exactly one XCD's L2) range. Nontemporal stores keep the 134 MB output
// stream from evicting x/srcTab.
// ---------------------------------------------------------------------------
__global__ __launch_bounds__(256) void gather_kernel(
    const f32x4* __restrict__ x, const int* __restrict__ srcTab,
    f32x4* __restrict__ out) {
  const int bid = (int)blockIdx.x;             // 0..16383
  const int lb = (bid & 7) * (16384 >> 3) + (bid >> 3);  // logical block
  const int row = (lb << 2) | ((int)threadIdx.x >> 6);   // [0, BB*MAXLEN)
  const int lane = (int)threadIdx.x & 63;
  const int b = row >> 12;                     // row / MAXLEN
  const int src = srcTab[row];                 // wave-uniform broadcast load

  f32x4* op = out + (size_t)row * (DD / 4);
  if (src < 0) {
    const f32x4 z = {0.f, 0.f, 0.f, 0.f};
    __builtin_nontemporal_store(z, op + lane);
    __builtin_nontemporal_store(z, op + lane + 64);
  } else {
    const f32x4* ip = x + ((size_t)b * TT + (size_t)src) * (DD / 4);
    const f32x4 a = ip[lane];
    const f32x4 c = ip[lane + 64];
    __builtin_nontemporal_store(a, op + lane);
    __builtin_nontemporal_store(c, op + lane + 64);
  }
}

extern "C" void kernel_launch(void* const* d_in, const int* in_sizes, int n_in,
                              void* d_out, int out_size, void* d_ws,
                              size_t ws_size, hipStream_t stream) {
  const float* x = (const float*)d_in[0];
  const int* dur = (const int*)d_in[1];
  int* srcTab = (int*)d_ws;  // BB*MAXLEN ints = 256 KiB

  build_src_kernel<<<BB, 1024, 0, stream>>>(dur, srcTab);

  const int rows = BB * MAXLEN;  // 65536 rows, 4 per block
  gather_kernel<<<rows / 4, 256, 0, stream>>>((const f32x4*)x, srcTab,
                                              (f32x4*)d_out);
}

// Round 2
// 165.914 us; speedup vs baseline: 1.0252x; 1.0252x over previous
//
#include <hip/hip_runtime.h>

// LengthRegulator: out[b,pos,:] = x[b, src(b,pos), :] masked by pos < total[b]
// B=16, T=1024, D=512, MAXLEN=4096 (fixed by setup_inputs()).

#define BB 16
#define TT 1024
#define DD 512
#define MAXLEN 4096

typedef float f32x4 __attribute__((ext_vector_type(4)));

// ---------------------------------------------------------------------------
// Kernel 1: per-batch cumsum + inverse src table.
// One block per batch, 1024 threads (1 per t). Wave-level shfl scan, one LDS
// round over the 16 wave sums, then each thread scatters its run (d <= 7 ints)
// and strided tail-fill of -1. Scatter clamped to MAXLEN (total can in theory
// exceed MAXLEN; reference clips there).
// ---------------------------------------------------------------------------
__global__ __launch_bounds__(1024) void build_src_kernel(
    const int* __restrict__ dur, int* __restrict__ srcTab) {
  const int b = blockIdx.x;
  const int t = threadIdx.x;     // 0..1023 == source index
  const int lane = t & 63;
  const int wid = t >> 6;        // 0..15

  __shared__ int wsum[16];

  int d = dur[b * TT + t];
  d = d > 0 ? d : 0;

  // inclusive scan within the wave
  int v = d;
#pragma unroll
  for (int off = 1; off < 64; off <<= 1) {
    int o = __shfl_up(v, off, 64);
    if (lane >= off) v += o;
  }
  if (lane == 63) wsum[wid] = v;
  __syncthreads();

  // exclusive base across waves + grand total (16 LDS broadcast reads)
  int base = 0, total = 0;
#pragma unroll
  for (int w = 0; w < 16; ++w) {
    const int s = wsum[w];
    total += s;
    if (w < wid) base += s;
  }
  const int incl = base + v;   // csum through t inclusive

  int* st = srcTab + b * MAXLEN;
  const int end = incl < MAXLEN ? incl : MAXLEN;
  for (int p = incl - d; p < end; ++p) st[p] = t;           // run of length d
  for (int p = total + t; p < MAXLEN; p += 1024) st[p] = -1;  // masked tail
}

// ---------------------------------------------------------------------------
// Kernel 2: 2 rows per wave (one int2 srcTab load -> two independent gather
// chains per lane: 4x 16B loads + 4x 16B nontemporal stores). 8 rows per
// 256-thread block; 8192 blocks. Row pairs stay within one batch (8 | 4096).
// ---------------------------------------------------------------------------
__global__ __launch_bounds__(256) void gather_kernel(
    const f32x4* __restrict__ x, const int* __restrict__ srcTab,
    f32x4* __restrict__ out) {
  const int wid = (int)threadIdx.x >> 6;
  const int lane = (int)threadIdx.x & 63;
  const int row0 = (int)blockIdx.x * 8 + wid * 2;  // [0, BB*MAXLEN), even
  const int b = row0 >> 12;                        // row / MAXLEN

  const int2 s2 = *reinterpret_cast<const int2*>(srcTab + row0);  // uniform

  const f32x4* xb = x + (size_t)b * (TT * (DD / 4));
  f32x4 a0 = {0.f, 0.f, 0.f, 0.f}, a1 = a0, c0 = a0, c1 = a0;
  if (s2.x >= 0) {
    const f32x4* ip = xb + (size_t)s2.x * (DD / 4);
    a0 = ip[lane];
    a1 = ip[lane + 64];
  }
  if (s2.y >= 0) {
    const f32x4* ip = xb + (size_t)s2.y * (DD / 4);
    c0 = ip[lane];
    c1 = ip[lane + 64];
  }

  f32x4* op = out + (size_t)row0 * (DD / 4);
  __builtin_nontemporal_store(a0, op + lane);
  __builtin_nontemporal_store(a1, op + lane + 64);
  __builtin_nontemporal_store(c0, op + 128 + lane);
  __builtin_nontemporal_store(c1, op + 128 + lane + 64);
}

extern "C" void kernel_launch(void* const* d_in, const int* in_sizes, int n_in,
                              void* d_out, int out_size, void* d_ws,
                              size_t ws_size, hipStream_t stream) {
  const float* x = (const float*)d_in[0];
  const int* dur = (const int*)d_in[1];
  int* srcTab = (int*)d_ws;  // BB*MAXLEN ints = 256 KiB

  build_src_kernel<<<BB, 1024, 0, stream>>>(dur, srcTab);

  const int rows = BB * MAXLEN;  // 65536 rows, 8 per block
  gather_kernel<<<rows / 8, 256, 0, stream>>>((const f32x4*)x, srcTab,
                                              (f32x4*)d_out);
}